// Round 1
// baseline (617.123 us; speedup 1.0000x reference)
//
#include <hip/hip_runtime.h>
#include <math.h>

#define BB 4096
#define DD 2048
#define CC 10000
#define KK 10
#define NT 256
#define NW 4
#define NF4 2500  // CC / 4
#define TRI(k) ((k)*((k)+1)/2)

// ---------------- Fused kernel: topk + Gram/Cholesky augmentation -------------
// Phase A: top-10 SET per row (order irrelevant downstream: projection subspace,
//          margins, and min-over-k are permutation invariant). Wave-local
//          shuffle argmax rounds, then wave 0 merges 40 candidates -> s_kidx.
// Phase B pass 1: accumulate G = A A^T (55), m = A z (10), v = A noise (10),
//          KEEPING A resident in registers (a0/a1, 80 VGPRs) so pass 2 needs
//          no W re-gather (saves ~160 MB L2-fill + a full L3-latency exposure).
// Wave 0: Cholesky solve G c = v (chol diag == |R_kk|, maps the 1e-6 rank
//          threshold exactly; redundant across wave-0 lanes).
// Phase B pass 2: out = z + scale * (noise - A^T c) from registers only.
__global__ __launch_bounds__(NT, 2) void fused_kernel(
    const float* __restrict__ logits, const int* __restrict__ y,
    const float* __restrict__ z, const float* __restrict__ W,
    const float* __restrict__ noise, float* __restrict__ out, int write_tail)
{
    __shared__ float s_cv[NW * KK];
    __shared__ int   s_ci[NW * KK];
    __shared__ int   s_kidx[KK];
    __shared__ float s_part[NW][80];   // 75 used
    __shared__ float s_sol[16];        // cvec[10], scale, valid

    const int b = blockIdx.x, tid = threadIdx.x;
    const int lane = tid & 63, wave = tid >> 6;
    const int yb = y[b];

    // ---------------- Phase A: top-10 ----------------
    {
        float4 lg[10];
        const float4* lrow = (const float4*)(logits + (size_t)b * CC);
        #pragma unroll
        for (int j = 0; j < 10; ++j) {
            const int i4 = tid + 256 * j;
            if (i4 < NF4) lg[j] = lrow[i4];
            else          lg[j] = make_float4(-3e38f, -3e38f, -3e38f, -3e38f);
        }
        #pragma unroll
        for (int j = 0; j < 10; ++j) {        // mask true class
            const int rel = yb - 4 * (tid + 256 * j);
            if (rel == 0) lg[j].x = -3e38f;
            else if (rel == 1) lg[j].y = -3e38f;
            else if (rel == 2) lg[j].z = -3e38f;
            else if (rel == 3) lg[j].w = -3e38f;
        }

        float lbest; int lbidx;
        auto rescan = [&]() {
            lbest = -3.1e38f; lbidx = 0x7fffffff;
            #pragma unroll
            for (int j = 0; j < 10; ++j) {
                const int base = 4 * (tid + 256 * j);
                if (lg[j].x > lbest) { lbest = lg[j].x; lbidx = base + 0; }
                if (lg[j].y > lbest) { lbest = lg[j].y; lbidx = base + 1; }
                if (lg[j].z > lbest) { lbest = lg[j].z; lbidx = base + 2; }
                if (lg[j].w > lbest) { lbest = lg[j].w; lbidx = base + 3; }
            }
        };
        rescan();

        // 10 wave-local rounds, no barriers
        for (int r = 0; r < KK; ++r) {
            float bv = lbest; int bi = lbidx;
            #pragma unroll
            for (int off = 32; off > 0; off >>= 1) {
                const float ov = __shfl_down(bv, off, 64);
                const int   oi = __shfl_down(bi, off, 64);
                if (ov > bv || (ov == bv && oi < bi)) { bv = ov; bi = oi; }
            }
            bv = __shfl(bv, 0, 64);
            bi = __shfl(bi, 0, 64);
            if (lane == 0) { s_cv[wave * KK + r] = bv; s_ci[wave * KK + r] = bi; }
            if (lbidx == bi) { // owner invalidates its element and rescans
                const int jw = ((bi >> 2) - tid) >> 8;
                const int cw = bi & 3;
                #pragma unroll
                for (int j = 0; j < 10; ++j) if (j == jw) {
                    if (cw == 0) lg[j].x = -3e38f;
                    else if (cw == 1) lg[j].y = -3e38f;
                    else if (cw == 2) lg[j].z = -3e38f;
                    else lg[j].w = -3e38f;
                }
                rescan();
            }
        }
    }
    __syncthreads();

    if (wave == 0) { // select top-10 of the 40 wave candidates -> LDS
        float cv = (lane < NW * KK) ? s_cv[lane] : -3.1e38f;
        int   ci = (lane < NW * KK) ? s_ci[lane] : 0x7fffffff;
        for (int r = 0; r < KK; ++r) {
            float bv = cv; int bi = ci;
            #pragma unroll
            for (int off = 32; off > 0; off >>= 1) {
                const float ov = __shfl_down(bv, off, 64);
                const int   oi = __shfl_down(bi, off, 64);
                if (ov > bv || (ov == bv && oi < bi)) { bv = ov; bi = oi; }
            }
            bi = __shfl(bi, 0, 64);
            if (lane == 0) s_kidx[r] = bi;
            if (ci == bi) cv = -3.1e38f;   // remove winner
        }
    }
    __syncthreads();

    // ---------------- Phase B pass 1 ----------------
    const size_t zoff = (size_t)b * DD;
    const size_t wyo  = (size_t)yb * DD;
    const float4 z0 = ((const float4*)(z + zoff))[tid];
    const float4 z1 = ((const float4*)(z + zoff + 1024))[tid];
    const float4 n0 = ((const float4*)(noise + zoff))[tid];
    const float4 n1 = ((const float4*)(noise + zoff + 1024))[tid];

    float acc[75];
    #pragma unroll
    for (int t = 0; t < 75; ++t) acc[t] = 0.0f;

    float4 a0[KK], a1[KK];   // A rows resident for pass 2 (no W re-gather)
    {
        int kidx[KK];
        #pragma unroll
        for (int k = 0; k < KK; ++k) kidx[k] = s_kidx[k];

        const float4 wy0 = ((const float4*)(W + wyo))[tid];
        #pragma unroll
        for (int k = 0; k < KK; ++k) {
            const float4 wk4 = ((const float4*)(W + (size_t)kidx[k] * DD))[tid];
            a0[k].x = wy0.x - wk4.x; a0[k].y = wy0.y - wk4.y;
            a0[k].z = wy0.z - wk4.z; a0[k].w = wy0.w - wk4.w;
        }
        const float4 wy1 = ((const float4*)(W + wyo + 1024))[tid];
        #pragma unroll
        for (int k = 0; k < KK; ++k) {
            const float4 wk4 = ((const float4*)(W + (size_t)kidx[k] * DD + 1024))[tid];
            a1[k].x = wy1.x - wk4.x; a1[k].y = wy1.y - wk4.y;
            a1[k].z = wy1.z - wk4.z; a1[k].w = wy1.w - wk4.w;
        }
    }

    auto accum = [&](const float4 (&a)[KK], const float4& zc, const float4& nc) {
        const float ze[4] = {zc.x, zc.y, zc.z, zc.w};
        const float ne[4] = {nc.x, nc.y, nc.z, nc.w};
        #pragma unroll
        for (int e = 0; e < 4; ++e) {
            float ak[KK];
            #pragma unroll
            for (int k = 0; k < KK; ++k)
                ak[k] = (e == 0) ? a[k].x : (e == 1) ? a[k].y : (e == 2) ? a[k].z : a[k].w;
            #pragma unroll
            for (int k = 0; k < KK; ++k) {
                acc[55 + k] += ak[k] * ze[e];
                acc[65 + k] += ak[k] * ne[e];
                #pragma unroll
                for (int j = 0; j <= k; ++j)
                    acc[TRI(k) + j] += ak[j] * ak[k];
            }
        }
    };
    accum(a0, z0, n0);
    accum(a1, z1, n1);

    // block reduce all 75 scalars (one phase)
    #pragma unroll
    for (int t = 0; t < 75; ++t) {
        float x = acc[t];
        #pragma unroll
        for (int off = 32; off > 0; off >>= 1) x += __shfl_down(x, off, 64);
        if (lane == 0) s_part[wave][t] = x;
    }
    __syncthreads();

    if (wave == 0) {   // Cholesky + triangular solves, redundant across wave 0
        float g[75];
        #pragma unroll
        for (int t = 0; t < 75; ++t)
            g[t] = s_part[0][t] + s_part[1][t] + s_part[2][t] + s_part[3][t];

        float dinv[KK];
        unsigned keepmask = 0u;
        #pragma unroll
        for (int k = 0; k < KK; ++k) {
            float s = g[TRI(k) + k];
            #pragma unroll
            for (int j = 0; j < KK; ++j) if (j < k) { const float l = g[TRI(k) + j]; s -= l * l; }
            const float dkk = sqrtf(fmaxf(s, 0.0f));
            const bool kp = dkk > 1e-6f;
            if (kp) keepmask |= (1u << k);
            dinv[k] = kp ? 1.0f / dkk : 0.0f;
            g[TRI(k) + k] = dkk;
            #pragma unroll
            for (int i = 0; i < KK; ++i) if (i > k) {
                float t2 = g[TRI(i) + k];
                #pragma unroll
                for (int j = 0; j < KK; ++j) if (j < k) t2 -= g[TRI(i) + j] * g[TRI(k) + j];
                g[TRI(i) + k] = t2 * dinv[k];
            }
        }
        float cvec[KK];
        #pragma unroll
        for (int i = 0; i < KK; ++i) {
            float s = g[65 + i];
            #pragma unroll
            for (int j = 0; j < KK; ++j) if (j < i) s -= g[TRI(i) + j] * cvec[j];
            cvec[i] = s * dinv[i];
        }
        #pragma unroll
        for (int i = KK - 1; i >= 0; --i) {
            float s = cvec[i];
            #pragma unroll
            for (int j = 0; j < KK; ++j) if (j > i) s -= g[TRI(j) + i] * cvec[j];
            cvec[i] = s * dinv[i];
        }
        const float denomf = 6.9914645e-8f;   // 2*EPS*log(20) + EPS (fp32)
        float amin = 3.0e38f;
        #pragma unroll
        for (int k = 0; k < KK; ++k) {
            const float sl = fmaxf(g[55 + k], 0.0f);   // GAMMA = 0
            amin = fminf(amin, sl * sl / denomf);
        }
        const bool valid = (keepmask != 0u) && (amin > 0.0f) && isfinite(amin);
        const float scale = valid ? sqrtf(amin) : 0.0f;
        if (lane == 0) {
            #pragma unroll
            for (int k = 0; k < KK; ++k) s_sol[k] = cvec[k];
            s_sol[10] = scale;
            s_sol[11] = valid ? 1.0f : 0.0f;
        }
    }
    __syncthreads();

    float cvec[KK];
    #pragma unroll
    for (int k = 0; k < KK; ++k) cvec[k] = s_sol[k];
    const float scale = s_sol[10];

    // ---------------- Phase B pass 2: pure register math ----------------
    auto emit = [&](const float4 (&a)[KK], const float4& zc, const float4& nc,
                    size_t coff) {
        float4 proj = make_float4(0.f, 0.f, 0.f, 0.f);
        #pragma unroll
        for (int k = 0; k < KK; ++k) {
            proj.x += cvec[k] * a[k].x; proj.y += cvec[k] * a[k].y;
            proj.z += cvec[k] * a[k].z; proj.w += cvec[k] * a[k].w;
        }
        float4 o;
        o.x = zc.x + scale * (nc.x - proj.x);
        o.y = zc.y + scale * (nc.y - proj.y);
        o.z = zc.z + scale * (nc.z - proj.z);
        o.w = zc.w + scale * (nc.w - proj.w);
        ((float4*)(out + zoff + coff))[tid] = o;
    };
    emit(a0, z0, n0, 0);
    emit(a1, z1, n1, 1024);

    if (write_tail && tid == 0) {
        out[(size_t)BB * DD + b] = (float)yb;
        out[(size_t)BB * DD + BB + b] = s_sol[11];
    }
}

extern "C" void kernel_launch(void* const* d_in, const int* in_sizes, int n_in,
                              void* d_out, int out_size, void* d_ws, size_t ws_size,
                              hipStream_t stream) {
    const float* z      = (const float*)d_in[0];
    const int*   y      = (const int*)d_in[1];
    const float* logits = (const float*)d_in[2];
    const float* W      = (const float*)d_in[3];
    const float* noise  = (const float*)d_in[4];
    float* out = (float*)d_out;
    const int write_tail = (out_size >= BB * DD + 2 * BB) ? 1 : 0;

    fused_kernel<<<BB, NT, 0, stream>>>(logits, y, z, W, noise, out, write_tail);
}

// Round 2
// 455.444 us; speedup vs baseline: 1.3550x; 1.3550x over previous
//
#include <hip/hip_runtime.h>
#include <math.h>

#define BB 4096
#define DD 2048
#define CC 10000
#define KK 10
#define NT 256
#define NW 4
#define NF4 2500  // CC / 4
#define TRI(k) ((k)*((k)+1)/2)

// Gram pair tables: accumulator t in [0,55) is pair (PJ[t], PK[t]), j<=k.
constexpr int PJ[55] = {0, 0,1, 0,1,2, 0,1,2,3, 0,1,2,3,4, 0,1,2,3,4,5,
                        0,1,2,3,4,5,6, 0,1,2,3,4,5,6,7, 0,1,2,3,4,5,6,7,8,
                        0,1,2,3,4,5,6,7,8,9};
constexpr int PK[55] = {0, 1,1, 2,2,2, 3,3,3,3, 4,4,4,4,4, 5,5,5,5,5,5,
                        6,6,6,6,6,6,6, 7,7,7,7,7,7,7,7, 8,8,8,8,8,8,8,8,8,
                        9,9,9,9,9,9,9,9,9,9};

// ---------------- Kernel 1: top-10 SET per row (unchanged, known-good) -------
__global__ __launch_bounds__(NT, 6) void topk_kernel(
    const float* __restrict__ logits, const int* __restrict__ y,
    int* __restrict__ topk)
{
    __shared__ float s_cv[NW * KK];
    __shared__ int   s_ci[NW * KK];

    const int b = blockIdx.x, tid = threadIdx.x;
    const int lane = tid & 63, wave = tid >> 6;
    const int yb = y[b];

    float4 lg[10];
    const float4* lrow = (const float4*)(logits + (size_t)b * CC);
    #pragma unroll
    for (int j = 0; j < 10; ++j) {
        const int i4 = tid + 256 * j;
        if (i4 < NF4) lg[j] = lrow[i4];
        else          lg[j] = make_float4(-3e38f, -3e38f, -3e38f, -3e38f);
    }
    #pragma unroll
    for (int j = 0; j < 10; ++j) {        // mask true class
        const int rel = yb - 4 * (tid + 256 * j);
        if (rel == 0) lg[j].x = -3e38f;
        else if (rel == 1) lg[j].y = -3e38f;
        else if (rel == 2) lg[j].z = -3e38f;
        else if (rel == 3) lg[j].w = -3e38f;
    }

    float lbest; int lbidx;
    auto rescan = [&]() {
        lbest = -3.1e38f; lbidx = 0x7fffffff;
        #pragma unroll
        for (int j = 0; j < 10; ++j) {
            const int base = 4 * (tid + 256 * j);
            if (lg[j].x > lbest) { lbest = lg[j].x; lbidx = base + 0; }
            if (lg[j].y > lbest) { lbest = lg[j].y; lbidx = base + 1; }
            if (lg[j].z > lbest) { lbest = lg[j].z; lbidx = base + 2; }
            if (lg[j].w > lbest) { lbest = lg[j].w; lbidx = base + 3; }
        }
    };
    rescan();

    for (int r = 0; r < KK; ++r) {        // 10 wave-local rounds, no barriers
        float bv = lbest; int bi = lbidx;
        #pragma unroll
        for (int off = 32; off > 0; off >>= 1) {
            const float ov = __shfl_down(bv, off, 64);
            const int   oi = __shfl_down(bi, off, 64);
            if (ov > bv || (ov == bv && oi < bi)) { bv = ov; bi = oi; }
        }
        bv = __shfl(bv, 0, 64);
        bi = __shfl(bi, 0, 64);
        if (lane == 0) { s_cv[wave * KK + r] = bv; s_ci[wave * KK + r] = bi; }
        if (lbidx == bi) {
            const int jw = ((bi >> 2) - tid) >> 8;
            const int cw = bi & 3;
            #pragma unroll
            for (int j = 0; j < 10; ++j) if (j == jw) {
                if (cw == 0) lg[j].x = -3e38f;
                else if (cw == 1) lg[j].y = -3e38f;
                else if (cw == 2) lg[j].z = -3e38f;
                else lg[j].w = -3e38f;
            }
            rescan();
        }
    }
    __syncthreads();

    if (wave == 0) {                       // top-10 of the 40 wave candidates
        float cv = (lane < NW * KK) ? s_cv[lane] : -3.1e38f;
        int   ci = (lane < NW * KK) ? s_ci[lane] : 0x7fffffff;
        for (int r = 0; r < KK; ++r) {
            float bv = cv; int bi = ci;
            #pragma unroll
            for (int off = 32; off > 0; off >>= 1) {
                const float ov = __shfl_down(bv, off, 64);
                const int   oi = __shfl_down(bi, off, 64);
                if (ov > bv || (ov == bv && oi < bi)) { bv = ov; bi = oi; }
            }
            bi = __shfl(bi, 0, 64);
            if (lane == 0) topk[b * KK + r] = bi;
            if (ci == bi) cv = -3.1e38f;
        }
    }
}

// ---------------- Pass-1 helper: wave-owned accumulator slice ----------------
// Wave scans the FULL D range (8 iters x 64 lanes x float4) and accumulates
// only its CNT of the 75 reduction outputs -> ~19 acc regs/thread instead of
// 75 (the round-0 spill source). NROW = rows this slice actually touches.
template<int LO, int CNT, int NROW, bool WZN>
__device__ __forceinline__ void pass1_accum(
    const float* __restrict__ W, const float* __restrict__ z,
    const float* __restrict__ noise, size_t wyo, size_t zoff,
    const int* kidx, int lane, float* s_g)
{
    float acc[CNT];
    #pragma unroll
    for (int t = 0; t < CNT; ++t) acc[t] = 0.0f;

    #pragma unroll 1   // keep regs low; TLP (16 waves/CU) hides gather latency
    for (int it = 0; it < 8; ++it) {
        const int p = lane + (it << 6);
        const float4 wy4 = ((const float4*)(W + wyo))[p];
        float4 a4[NROW];
        #pragma unroll
        for (int k = 0; k < NROW; ++k) {
            const float4 wk4 = ((const float4*)(W + (size_t)kidx[k] * DD))[p];
            a4[k].x = wy4.x - wk4.x; a4[k].y = wy4.y - wk4.y;
            a4[k].z = wy4.z - wk4.z; a4[k].w = wy4.w - wk4.w;
        }
        float4 z4 = make_float4(0.f, 0.f, 0.f, 0.f), n4 = z4;
        if (WZN) {
            z4 = ((const float4*)(z + zoff))[p];
            n4 = ((const float4*)(noise + zoff))[p];
        }
        #pragma unroll
        for (int e = 0; e < 4; ++e) {
            float ak[NROW];
            #pragma unroll
            for (int k = 0; k < NROW; ++k)
                ak[k] = (e == 0) ? a4[k].x : (e == 1) ? a4[k].y
                      : (e == 2) ? a4[k].z : a4[k].w;
            const float ze = (e == 0) ? z4.x : (e == 1) ? z4.y : (e == 2) ? z4.z : z4.w;
            const float ne = (e == 0) ? n4.x : (e == 1) ? n4.y : (e == 2) ? n4.z : n4.w;
            #pragma unroll
            for (int t = 0; t < CNT; ++t) {
                const int g = LO + t;                    // compile-time constant
                if (g < 55)      acc[t] += ak[PJ[g < 55 ? g : 0]] * ak[PK[g < 55 ? g : 0]];
                else if (g < 65) acc[t] += ak[(g - 55) < NROW ? (g - 55) : 0] * ze;
                else             acc[t] += ak[(g - 65) < NROW ? (g - 65) : 0] * ne;
            }
        }
    }
    // wave covered all of D -> shuffle reduce is the FULL sum, no cross-wave add
    #pragma unroll
    for (int t = 0; t < CNT; ++t) {
        float x = acc[t];
        #pragma unroll
        for (int off = 32; off > 0; off >>= 1) x += __shfl_down(x, off, 64);
        if (lane == 0) s_g[LO + t] = x;
    }
}

// ---------------- Kernel 2: Gram/Cholesky augmentation -----------------------
// acc split across waves: w0 t[0,19) rows<=5 | w1 t[19,38) rows<=8 |
// w2 t[38,55) rows<=9 | w3 t[55,75) = m,v (all rows + z + noise).
// ~19 acc + transient a4 => no scratch spills, 4 blocks/CU.
__global__ __launch_bounds__(NT, 4) void aug_kernel(
    const float* __restrict__ z, const int* __restrict__ y,
    const float* __restrict__ W, const float* __restrict__ noise,
    const int* __restrict__ topk, float* __restrict__ out, int write_tail)
{
    __shared__ float s_g[80];          // 75 used: Gram(55), m(10), v(10)
    __shared__ float s_sol[16];        // cvec[10], scale, valid

    const int b = blockIdx.x, tid = threadIdx.x;
    const int lane = tid & 63, wave = tid >> 6;
    const int yb = y[b];

    int kidx[KK];
    #pragma unroll
    for (int k = 0; k < KK; ++k) kidx[k] = topk[b * KK + k];

    const size_t zoff = (size_t)b * DD;
    const size_t wyo  = (size_t)yb * DD;

    if (wave == 0)      pass1_accum< 0, 19,  6, false>(W, z, noise, wyo, zoff, kidx, lane, s_g);
    else if (wave == 1) pass1_accum<19, 19,  9, false>(W, z, noise, wyo, zoff, kidx, lane, s_g);
    else if (wave == 2) pass1_accum<38, 17, 10, false>(W, z, noise, wyo, zoff, kidx, lane, s_g);
    else                pass1_accum<55, 20, 10, true >(W, z, noise, wyo, zoff, kidx, lane, s_g);
    __syncthreads();

    if (wave == 0) {   // Cholesky + triangular solves, redundant across wave 0
        float g[75];
        #pragma unroll
        for (int t = 0; t < 75; ++t) g[t] = s_g[t];

        float dinv[KK];
        unsigned keepmask = 0u;
        #pragma unroll
        for (int k = 0; k < KK; ++k) {
            float s = g[TRI(k) + k];
            #pragma unroll
            for (int j = 0; j < KK; ++j) if (j < k) { const float l = g[TRI(k) + j]; s -= l * l; }
            const float dkk = sqrtf(fmaxf(s, 0.0f));
            const bool kp = dkk > 1e-6f;
            if (kp) keepmask |= (1u << k);
            dinv[k] = kp ? 1.0f / dkk : 0.0f;
            g[TRI(k) + k] = dkk;
            #pragma unroll
            for (int i = 0; i < KK; ++i) if (i > k) {
                float t2 = g[TRI(i) + k];
                #pragma unroll
                for (int j = 0; j < KK; ++j) if (j < k) t2 -= g[TRI(i) + j] * g[TRI(k) + j];
                g[TRI(i) + k] = t2 * dinv[k];
            }
        }
        float cvec[KK];
        #pragma unroll
        for (int i = 0; i < KK; ++i) {
            float s = g[65 + i];
            #pragma unroll
            for (int j = 0; j < KK; ++j) if (j < i) s -= g[TRI(i) + j] * cvec[j];
            cvec[i] = s * dinv[i];
        }
        #pragma unroll
        for (int i = KK - 1; i >= 0; --i) {
            float s = cvec[i];
            #pragma unroll
            for (int j = 0; j < KK; ++j) if (j > i) s -= g[TRI(j) + i] * cvec[j];
            cvec[i] = s * dinv[i];
        }
        const float denomf = 6.9914645e-8f;   // 2*EPS*log(20) + EPS (fp32)
        float amin = 3.0e38f;
        #pragma unroll
        for (int k = 0; k < KK; ++k) {
            const float sl = fmaxf(g[55 + k], 0.0f);   // GAMMA = 0
            amin = fminf(amin, sl * sl / denomf);
        }
        const bool valid = (keepmask != 0u) && (amin > 0.0f) && isfinite(amin);
        const float scale = valid ? sqrtf(amin) : 0.0f;
        if (lane == 0) {
            #pragma unroll
            for (int k = 0; k < KK; ++k) s_sol[k] = cvec[k];
            s_sol[10] = scale;
            s_sol[11] = valid ? 1.0f : 0.0f;
        }
    }
    __syncthreads();

    float cvec[KK];
    #pragma unroll
    for (int k = 0; k < KK; ++k) cvec[k] = s_sol[k];
    const float scale = s_sol[10];

    // pass 2: re-gather W chunks (L1/L2-hot), project, write out
    #pragma unroll
    for (int c = 0; c < 2; ++c) {
        const size_t coff = (size_t)c * 1024;
        const float4 wy4 = ((const float4*)(W + wyo + coff))[tid];
        float4 proj = make_float4(0.f, 0.f, 0.f, 0.f);
        float csum = 0.f;
        #pragma unroll
        for (int k = 0; k < KK; ++k) {
            const float4 wk4 = ((const float4*)(W + (size_t)kidx[k] * DD + coff))[tid];
            proj.x -= cvec[k] * wk4.x; proj.y -= cvec[k] * wk4.y;
            proj.z -= cvec[k] * wk4.z; proj.w -= cvec[k] * wk4.w;
            csum += cvec[k];
        }
        proj.x += csum * wy4.x; proj.y += csum * wy4.y;
        proj.z += csum * wy4.z; proj.w += csum * wy4.w;
        const float4 zc = ((const float4*)(z + zoff + coff))[tid];
        const float4 nc = ((const float4*)(noise + zoff + coff))[tid];
        float4 o;
        o.x = zc.x + scale * (nc.x - proj.x);
        o.y = zc.y + scale * (nc.y - proj.y);
        o.z = zc.z + scale * (nc.z - proj.z);
        o.w = zc.w + scale * (nc.w - proj.w);
        ((float4*)(out + zoff + coff))[tid] = o;
    }

    if (write_tail && tid == 0) {
        out[(size_t)BB * DD + b] = (float)yb;
        out[(size_t)BB * DD + BB + b] = s_sol[11];
    }
}

extern "C" void kernel_launch(void* const* d_in, const int* in_sizes, int n_in,
                              void* d_out, int out_size, void* d_ws, size_t ws_size,
                              hipStream_t stream) {
    const float* z      = (const float*)d_in[0];
    const int*   y      = (const int*)d_in[1];
    const float* logits = (const float*)d_in[2];
    const float* W      = (const float*)d_in[3];
    const float* noise  = (const float*)d_in[4];
    float* out = (float*)d_out;
    int* topk = (int*)d_ws;   // BB*KK ints

    topk_kernel<<<BB, NT, 0, stream>>>(logits, y, topk);
    const int write_tail = (out_size >= BB * DD + 2 * BB) ? 1 : 0;
    aug_kernel<<<BB, NT, 0, stream>>>(z, y, W, noise, topk, out, write_tail);
}